// Round 7
// baseline (313.969 us; speedup 1.0000x reference)
//
#include <hip/hip_runtime.h>

// NeRF volume renderer, fp32.
// Inputs (setup_inputs order):
//   0 rays_o  [N,3]   1 rays_d [N,3]   2 sigmas [N,S]   3 rgbs [N,S,3]
//   4 sun_v   [N,S]   5 sky    [N,S,3] 6 nears  [N]     7 fars [N]
//   8 density_grid [G,G,G]
// Output: image [N,3] ++ depth [N] ++ weights_sum [N]  (flat f32)
//
// R6 post-mortem: 98.6us, 39% HBM, FETCH ideal, VALU 32%, VGPR 24 ->
// latency/MLP-bound (4KB in flight/wave vs 9KB/CU needed). This version:
// 2 rays/wave (32-lane segments), 4 samples/lane, float4 streams ->
// 8KB in flight/wave, half the VMEM instructions, 2.4x fewer DS ops/sample.

#define NRAYS  65536
#define NSTEPS 128
#define GRIDN  128

typedef float v4f __attribute__((ext_vector_type(4)));

// t/xyz/index use __fadd_rn/__fmul_rn: hipcc's -ffp-contract=fast would
// fma-contract them, diverging from XLA's separate mul+add on the
// branch-amplified occupancy/inside test path.
__global__ __launch_bounds__(256, 4) void nerf_render_kernel(
    const float* __restrict__ rays_o,
    const float* __restrict__ rays_d,
    const float* __restrict__ sigmas,
    const float* __restrict__ rgbs,
    const float* __restrict__ sun_v,
    const float* __restrict__ sky,
    const float* __restrict__ nears,
    const float* __restrict__ fars,
    const float* __restrict__ grid,
    float* __restrict__ out)
{
    const int tid  = blockIdx.x * blockDim.x + threadIdx.x;
    const int wave = tid >> 6;                 // global wave id
    const int lane = threadIdx.x & 63;
    const int half = lane >> 5;                // which ray of the pair
    const int l32  = lane & 31;                // lane within 32-lane segment
    const int ray  = wave * 2 + half;

    const float nearv = nears[ray];
    const float farv  = fars[ray];
    const float dt    = (farv - nearv) * (1.0f / NSTEPS);

    const float ox = rays_o[ray * 3 + 0];
    const float oy = rays_o[ray * 3 + 1];
    const float oz = rays_o[ray * 3 + 2];
    const float dx = rays_d[ray * 3 + 0];
    const float dy = rays_d[ray * 3 + 1];
    const float dz = rays_d[ray * 3 + 2];

    const int  s0   = 4 * l32;                 // lane's first sample
    const long base = (long)ray * NSTEPS + s0; // 16B-aligned f32 streams

    // ---- streamed loads: 8 x 16B per lane, all in flight together ----
    const v4f sg = __builtin_nontemporal_load((const v4f*)(sigmas + base));
    const v4f sv = __builtin_nontemporal_load((const v4f*)(sun_v  + base));
    const v4f r0 = __builtin_nontemporal_load((const v4f*)(rgbs + base * 3));
    const v4f r1 = __builtin_nontemporal_load((const v4f*)(rgbs + base * 3 + 4));
    const v4f r2 = __builtin_nontemporal_load((const v4f*)(rgbs + base * 3 + 8));
    const v4f k0 = __builtin_nontemporal_load((const v4f*)(sky  + base * 3));
    const v4f k1 = __builtin_nontemporal_load((const v4f*)(sky  + base * 3 + 4));
    const v4f k2 = __builtin_nontemporal_load((const v4f*)(sky  + base * 3 + 8));

    // sample j of this lane: rgb = e[3j..3j+2] over the 12 loaded floats
    const float rr_[4] = { r0[0], r0[3], r1[2], r2[1] };
    const float rg_[4] = { r0[1], r1[0], r1[3], r2[2] };
    const float rb_[4] = { r0[2], r1[1], r2[0], r2[3] };
    const float kr_[4] = { k0[0], k0[3], k1[2], k2[1] };
    const float kg_[4] = { k0[1], k1[0], k1[3], k2[2] };
    const float kb_[4] = { k0[2], k1[1], k2[0], k2[3] };

    float t_[4], tau_[4], cr_[4], cg_[4], cb_[4];

    #pragma unroll
    for (int j = 0; j < 4; ++j) {
        const int s = s0 + j;
        // separate mul/add rounding (no fma) on the branch-amplified path
        const float t = __fadd_rn(nearv, __fmul_rn((float)s + 0.5f, dt));
        const float x = __fadd_rn(ox, __fmul_rn(t, dx));
        const float y = __fadd_rn(oy, __fmul_rn(t, dy));
        const float z = __fadd_rn(oz, __fmul_rn(t, dz));

        // occupancy index: bit-identical to clip(int32((xyz+1)/2*128), 0, 127)
        int ix = (int)__fmul_rn(__fadd_rn(x, 1.0f), 64.0f);
        int iy = (int)__fmul_rn(__fadd_rn(y, 1.0f), 64.0f);
        int iz = (int)__fmul_rn(__fadd_rn(z, 1.0f), 64.0f);
        ix = min(max(ix, 0), GRIDN - 1);
        iy = min(max(iy, 0), GRIDN - 1);
        iz = min(max(iz, 0), GRIDN - 1);
        const float g = grid[((long)ix * GRIDN + iy) * GRIDN + iz];

        const bool inside = (fabsf(x) < 1.0f) & (fabsf(y) < 1.0f) & (fabsf(z) < 1.0f);
        const bool occ    = (g > 0.01f) & inside;

        const float sig = occ ? sg[j] : 0.0f;  // DENSITY_SCALE = 1

        // shading: rgb = rgbs * (sun_v + (1 - sun_v) * sky)
        const float s_v = sv[j];
        cr_[j] = rr_[j] * (s_v + (1.0f - s_v) * kr_[j]);
        cg_[j] = rg_[j] * (s_v + (1.0f - s_v) * kg_[j]);
        cb_[j] = rb_[j] * (s_v + (1.0f - s_v) * kb_[j]);

        t_[j]   = t;
        tau_[j] = sig * dt;
    }

    // ---- segmented exclusive scan of tau over the 128 samples of this ray ----
    // in-lane total, then 5-step shfl_up scan within the 32-lane segment.
    const float tot = tau_[0] + tau_[1] + tau_[2] + tau_[3];
    float incl = tot;
    #pragma unroll
    for (int off = 1; off < 32; off <<= 1) {
        const float u = __shfl_up(incl, off);
        if (l32 >= off) incl += u;             // guard also blocks cross-segment pulls
    }
    float run = incl - tot;                    // exclusive prefix at sample s0

    // ---- compositing weights + per-lane partial sums ----
    float wsum = 0.0f, dsum = 0.0f, ir = 0.0f, ig = 0.0f, ib = 0.0f;
    #pragma unroll
    for (int j = 0; j < 4; ++j) {
        const float T     = expf(-run);
        const float alpha = 1.0f - expf(-tau_[j]);
        const float w     = (T > 1e-3f) ? alpha * T : 0.0f;
        wsum += w; dsum += w * t_[j];
        ir += w * cr_[j]; ig += w * cg_[j]; ib += w * cb_[j];
        run += tau_[j];
    }

    // ---- segment reduction of the 5 sums (offsets <=16 stay in-segment) ----
    #pragma unroll
    for (int off = 16; off > 0; off >>= 1) {
        wsum += __shfl_xor(wsum, off);
        dsum += __shfl_xor(dsum, off);
        ir   += __shfl_xor(ir, off);
        ig   += __shfl_xor(ig, off);
        ib   += __shfl_xor(ib, off);
    }

    if (l32 == 0) {
        const float bgw = 1.0f - wsum;         // BG_COLOR = 1.0
        out[ray * 3 + 0] = ir + bgw;
        out[ray * 3 + 1] = ig + bgw;
        out[ray * 3 + 2] = ib + bgw;
        out[3 * NRAYS + ray] = fmaxf(dsum - nearv, 0.0f) / (farv - nearv);
        out[4 * NRAYS + ray] = wsum;
    }
}

extern "C" void kernel_launch(void* const* d_in, const int* in_sizes, int n_in,
                              void* d_out, int out_size, void* d_ws, size_t ws_size,
                              hipStream_t stream) {
    const float* rays_o = (const float*)d_in[0];
    const float* rays_d = (const float*)d_in[1];
    const float* sigmas = (const float*)d_in[2];
    const float* rgbs   = (const float*)d_in[3];
    const float* sun_v  = (const float*)d_in[4];
    const float* sky    = (const float*)d_in[5];
    const float* nears  = (const float*)d_in[6];
    const float* fars   = (const float*)d_in[7];
    const float* grid   = (const float*)d_in[8];
    float* out = (float*)d_out;

    const int threads = 256;                   // 4 waves = 8 rays per block
    const int blocks  = NRAYS / 8;             // 8192 blocks
    nerf_render_kernel<<<blocks, threads, 0, stream>>>(
        rays_o, rays_d, sigmas, rgbs, sun_v, sky, nears, fars, grid, out);
}

// Round 11
// 288.983 us; speedup vs baseline: 1.0865x; 1.0865x over previous
//
#include <hip/hip_runtime.h>

// NeRF volume renderer, fp32.
// Inputs (setup_inputs order):
//   0 rays_o  [N,3]   1 rays_d [N,3]   2 sigmas [N,S]   3 rgbs [N,S,3]
//   4 sun_v   [N,S]   5 sky    [N,S,3] 6 nears  [N]     7 fars [N]
//   8 density_grid [G,G,G]
// Output: image [N,3] ++ depth [N] ++ weights_sum [N]  (flat f32)
//
// R8 experiment (3rd resubmit after infra failures): exact R6 structure
// (1 ray/wave, v2f pair-per-lane, 98.6us baseline) with nontemporal load
// hints REMOVED (single-variable A/B). Theory: nt bypass throttles stream
// BW at ~3.2 TB/s (R6 and R7 both pinned there despite different
// structures); plain loads restore L2 merging/bursting.

#define NRAYS  65536
#define NSTEPS 128
#define GRIDN  128

typedef float v2f __attribute__((ext_vector_type(2)));

// One 64-lane wave per ray; lane l handles samples 2l and 2l+1.
// All per-stream loads are 8B (float2) and wave-contiguous.
// t/xyz use __fadd_rn/__fmul_rn: hipcc's -ffp-contract=fast would
// fma-contract them, diverging from XLA's separate mul+add on the
// branch-amplified occupancy/inside-test path.
__global__ __launch_bounds__(256, 4) void nerf_render_kernel(
    const float* __restrict__ rays_o,
    const float* __restrict__ rays_d,
    const float* __restrict__ sigmas,
    const float* __restrict__ rgbs,
    const float* __restrict__ sun_v,
    const float* __restrict__ sky,
    const float* __restrict__ nears,
    const float* __restrict__ fars,
    const float* __restrict__ grid,
    float* __restrict__ out)
{
    const int tid  = blockIdx.x * blockDim.x + threadIdx.x;
    const int ray  = tid >> 6;
    const int lane = threadIdx.x & 63;
    if (ray >= NRAYS) return;

    const float nearv = nears[ray];
    const float farv  = fars[ray];
    const float dt    = (farv - nearv) * (1.0f / NSTEPS);

    const float ox = rays_o[ray * 3 + 0];
    const float oy = rays_o[ray * 3 + 1];
    const float oz = rays_o[ray * 3 + 2];
    const float dx = rays_d[ray * 3 + 0];
    const float dy = rays_d[ray * 3 + 1];
    const float dz = rays_d[ray * 3 + 2];

    const int  s0   = 2 * lane;                    // first of the lane's two samples
    const long base = (long)ray * NSTEPS + s0;     // even -> 8B-aligned f32 streams

    // ---- streamed loads (plain cached loads; R8: nt removed) ----
    const v2f sg  = *(const v2f*)(sigmas + base);
    const v2f sv  = *(const v2f*)(sun_v  + base);
    const v2f r01 = *(const v2f*)(rgbs + base * 3);
    const v2f r23 = *(const v2f*)(rgbs + base * 3 + 2);
    const v2f r45 = *(const v2f*)(rgbs + base * 3 + 4);
    const v2f k01 = *(const v2f*)(sky  + base * 3);
    const v2f k23 = *(const v2f*)(sky  + base * 3 + 2);
    const v2f k45 = *(const v2f*)(sky  + base * 3 + 4);

    float t_[2], tau_[2], cr_[2], cg_[2], cb_[2];
    const float rr_[2] = { r01[0], r23[1] };
    const float rg_[2] = { r01[1], r45[0] };
    const float rb_[2] = { r23[0], r45[1] };
    const float kr_[2] = { k01[0], k23[1] };
    const float kg_[2] = { k01[1], k45[0] };
    const float kb_[2] = { k23[0], k45[1] };

    #pragma unroll
    for (int j = 0; j < 2; ++j) {
        const int s = s0 + j;
        // separate mul/add rounding (no fma) on the branch-amplified path
        const float t = __fadd_rn(nearv, __fmul_rn((float)s + 0.5f, dt));
        const float x = __fadd_rn(ox, __fmul_rn(t, dx));
        const float y = __fadd_rn(oy, __fmul_rn(t, dy));
        const float z = __fadd_rn(oz, __fmul_rn(t, dz));

        // occupancy index: bit-identical to clip(int32((xyz+1)/2*128), 0, 127)
        int ix = (int)__fmul_rn(__fadd_rn(x, 1.0f), 64.0f);
        int iy = (int)__fmul_rn(__fadd_rn(y, 1.0f), 64.0f);
        int iz = (int)__fmul_rn(__fadd_rn(z, 1.0f), 64.0f);
        ix = min(max(ix, 0), GRIDN - 1);
        iy = min(max(iy, 0), GRIDN - 1);
        iz = min(max(iz, 0), GRIDN - 1);
        const float g = grid[((long)ix * GRIDN + iy) * GRIDN + iz];

        const bool inside = (fabsf(x) < 1.0f) & (fabsf(y) < 1.0f) & (fabsf(z) < 1.0f);
        const bool occ    = (g > 0.01f) & inside;

        const float sig = occ ? sg[j] : 0.0f;      // DENSITY_SCALE = 1

        // shading: rgb = rgbs * (sun_v + (1 - sun_v) * sky)
        const float s_v = sv[j];
        cr_[j] = rr_[j] * (s_v + (1.0f - s_v) * kr_[j]);
        cg_[j] = rg_[j] * (s_v + (1.0f - s_v) * kg_[j]);
        cb_[j] = rb_[j] * (s_v + (1.0f - s_v) * kb_[j]);

        t_[j]   = t;
        tau_[j] = sig * dt;
    }

    // ---- exclusive prefix sum of tau over 128 samples: one wave scan ----
    const float pair = tau_[0] + tau_[1];
    float incl = pair;
    #pragma unroll
    for (int off = 1; off < 64; off <<= 1) {
        const float u = __shfl_up(incl, off);
        if (lane >= off) incl += u;
    }
    const float eLane = incl - pair;               // exclusive prefix of lane pairs
    const float excl_[2] = { eLane, eLane + tau_[0] };

    // ---- compositing weights + per-lane partial sums ----
    float wsum = 0.0f, dsum = 0.0f, ir = 0.0f, ig = 0.0f, ib = 0.0f;
    #pragma unroll
    for (int j = 0; j < 2; ++j) {
        const float T     = expf(-excl_[j]);
        const float alpha = 1.0f - expf(-tau_[j]);
        const float w     = (T > 1e-3f) ? alpha * T : 0.0f;
        wsum += w; dsum += w * t_[j];
        ir += w * cr_[j]; ig += w * cg_[j]; ib += w * cb_[j];
    }

    // ---- wave reduction of the 5 sums ----
    #pragma unroll
    for (int off = 32; off > 0; off >>= 1) {
        wsum += __shfl_xor(wsum, off);
        dsum += __shfl_xor(dsum, off);
        ir   += __shfl_xor(ir, off);
        ig   += __shfl_xor(ig, off);
        ib   += __shfl_xor(ib, off);
    }

    if (lane == 0) {
        const float bgw = 1.0f - wsum;             // BG_COLOR = 1.0
        out[ray * 3 + 0] = ir + bgw;
        out[ray * 3 + 1] = ig + bgw;
        out[ray * 3 + 2] = ib + bgw;
        out[3 * NRAYS + ray] = fmaxf(dsum - nearv, 0.0f) / (farv - nearv);
        out[4 * NRAYS + ray] = wsum;
    }
}

extern "C" void kernel_launch(void* const* d_in, const int* in_sizes, int n_in,
                              void* d_out, int out_size, void* d_ws, size_t ws_size,
                              hipStream_t stream) {
    const float* rays_o = (const float*)d_in[0];
    const float* rays_d = (const float*)d_in[1];
    const float* sigmas = (const float*)d_in[2];
    const float* rgbs   = (const float*)d_in[3];
    const float* sun_v  = (const float*)d_in[4];
    const float* sky    = (const float*)d_in[5];
    const float* nears  = (const float*)d_in[6];
    const float* fars   = (const float*)d_in[7];
    const float* grid   = (const float*)d_in[8];
    float* out = (float*)d_out;

    const int threads = 256;                      // 4 rays (waves) per block
    const int blocks  = (NRAYS * 64) / threads;   // 16384 blocks
    nerf_render_kernel<<<blocks, threads, 0, stream>>>(
        rays_o, rays_d, sigmas, rgbs, sun_v, sky, nears, fars, grid, out);
}